// Round 5
// baseline (495.275 us; speedup 1.0000x reference)
//
#include <hip/hip_runtime.h>
#include <hip/hip_bf16.h>

// Swin shifted-window attention, fully fused per-window. FP32 global IO,
// bf16 MFMA internals. B=4, H=W=256, C=192, NH=6, HD=32, WS=8, SHIFT=4, "SW".
// One block = one window (64 tokens), 768 threads = 12 waves.
// R2: LDS 139.5KB -> 79.5KB region reuse. R3: no reg clamp (spills).
// R4: bf16 fragment-packed weights in d_ws -> 1 dwordx4/fragment; regs fell
//     under the 2-block threshold (total<=~85/wave) -> 66% occupancy.
// R5: precompute bias+mask tables [4 variants][6 heads][64][64] bf16 in d_ws
//     (kills 3a's per-element rel-index math + scattered RELH LDS gather =
//     suspected bank-conflict source), fold SCALE into Q store, cache rolled
//     row offsets (ROWOFF) for phase-4 stores.

typedef __bf16 bf16x8 __attribute__((ext_vector_type(8)));
typedef float  f32x4  __attribute__((ext_vector_type(4)));

static __device__ __forceinline__ unsigned short f2bf(float f) {
    __bf16 h = (__bf16)f;                       // RNE f32->bf16
    return __builtin_bit_cast(unsigned short, h);
}
static __device__ __forceinline__ float bf2f(unsigned short u) {
    return (float)__builtin_bit_cast(__bf16, u);
}

// ---------------------------------------------------------------------------
// Workspace layout (bytes):
//   wpk  @ 0       : 147456 bf16 = 294912 B   (fragment-packed wq|wl)
//   btab @ 294912  :  98304 bf16 = 196608 B   ([vm][head][row][col] bias+mask)
// total 491520 B.

__global__ __launch_bounds__(256)
void pack_w(const float* __restrict__ wq, const float* __restrict__ wl,
            unsigned short* __restrict__ wp)
{
    int e = blockIdx.x * 256 + threadIdx.x;           // 0..147455
    if (e < 110592) {
        int j = e & 7, lane = (e >> 3) & 63, f = e >> 9;   // f = nt*6+ks
        int ks = f % 6, nt = f / 6;
        int s = nt / 12, wi = nt % 12;
        int row = ks * 32 + (lane >> 4) * 8 + j;
        int col = s * 192 + wi * 16 + (lane & 15);
        wp[e] = f2bf(wq[row * 576 + col]);
    } else {
        int e2 = e - 110592;
        int j = e2 & 7, lane = (e2 >> 3) & 63, f = e2 >> 9; // f = ntg*6+ks
        int ks = f % 6, ntg = f / 6;
        int row = ks * 32 + (lane >> 4) * 8 + j;
        int col = ntg * 16 + (lane & 15);
        wp[e] = f2bf(wl[row * 192 + col]);
    }
}

__global__ __launch_bounds__(256)
void pack_bias(const float* __restrict__ rel_pos, unsigned short* __restrict__ bt)
{
    int e = blockIdx.x * 256 + threadIdx.x;           // 0..98303: [vm][h][row][col]
    int col = e & 63, row = (e >> 6) & 63;
    int vh  = e >> 12;                                // 0..23
    int h   = vh % 6, vm = vh / 6;                    // vm = mH*2 + mW
    int r1 = row >> 3, c1 = row & 7, r2 = col >> 3, c2 = col & 7;
    float v = rel_pos[((r1 - r2 + 7) * 15 + (c1 - c2 + 7)) * 6 + h];
    bool masked = ((vm & 2) && ((r1 < 4) != (r2 < 4)))
               || ((vm & 1) && ((c1 < 4) != (c2 < 4)));
    bt[e] = f2bf(masked ? -1e30f : v);
}

// ---------------------------------------------------------------------------
// LDS layout (ushort units), total 39880 us = 79760 B  (2 blocks/CU):
//   A @ 0     (12800): XS 64x200 (phase1-2) -> VT 192x64 swz (2b-3b) -> OS 64x200
//   B @ 12800 (12800): QS 64x200  \ (phase2-3a) -> P: 12 waves x 32x64 swz
//   C @ 25600 (12800): KS 64x200  /              (24576 us, phase 3a-3b)
//   RELH @ 38400 (1350): rel_pos f16 (fallback path only)
//   ROWOFF @ 39752 (64 int): rolled global row offsets for phase-4 stores

template<bool PACKED>
__global__ __launch_bounds__(768)
void wmsa_fused(const float* __restrict__ x,        // [4,256,256,192]
                const float* __restrict__ wq,       // [192][576]
                const float* __restrict__ b_qkv,    // [576]
                const float* __restrict__ wl,       // [192][192]
                const float* __restrict__ b_lin,    // [192]
                const float* __restrict__ rel_pos,  // [225*6]
                const unsigned short* __restrict__ wp,    // packed weights (or null)
                const unsigned short* __restrict__ btab,  // packed bias tables (or null)
                float* __restrict__ out)            // [4,256,256,192]
{
    __shared__ __align__(16) unsigned short smem[39880];
    unsigned short* REGA = smem;            // XS -> VT(swz) -> OS
    unsigned short* QS   = smem + 12800;
    unsigned short* KS   = smem + 25600;
    _Float16*       RELH = (_Float16*)(smem + 38400);
    int*            ROWOFF = (int*)(smem + 39752);

    const int tid  = threadIdx.x;
    const int lane = tid & 63;
    const int w2   = tid >> 6;     // wave id 0..11
    const int l15  = lane & 15;
    const int quad = lane >> 4;

    const int bx = blockIdx.x;     // 4096 = 4 * 32 * 32
    const int b  = bx >> 10;
    const int wh = (bx >> 5) & 31;
    const int ww = bx & 31;

    const float SCALE = 0.17677669529663687f;         // 32^-0.5

    // ---- Phase 1: stage rolled x rows (64 tokens x 192, fp32 -> bf16)
    for (int i = tid; i < 3072; i += 768) {           // 64 rows * 48 float4 chunks
        int row = i / 48, cc = i % 48;
        int hs = wh * 8 + (row >> 3), wsx = ww * 8 + (row & 7);
        int ho = (hs + 4) & 255,      wo  = (wsx + 4) & 255;
        int base = ((((b << 8) + ho) << 8) + wo) * 192;
        if (cc == 0) ROWOFF[row] = base;              // reused by phase-4 stores
        float4 v = *(const float4*)(x + base + cc * 4);
        ushort4 p;
        p.x = f2bf(v.x); p.y = f2bf(v.y); p.z = f2bf(v.z); p.w = f2bf(v.w);
        *(ushort4*)(REGA + row * 200 + cc * 4) = p;
    }
    if (!PACKED)
        for (int i = tid; i < 1350; i += 768) RELH[i] = (_Float16)rel_pos[i];
    __syncthreads();                                  // bar1: XS(+ROWOFF) staged

    // ---- Phase 2: qkv = xs @ Wqkv + b_qkv. Wave w2 owns 16 cols of each of Q/K/V.
    const int colL = w2 * 16 + l15;                   // 0..191
    const unsigned short* fqQ = wp + (w2 * 6) * 512 + lane * 8;          // s=0
    const unsigned short* fqK = fqQ + 12 * 6 * 512;                      // s=1
    const unsigned short* fqV = fqQ + 24 * 6 * 512;                      // s=2
    f32x4 accV[4];
    {
        f32x4 acc[4];
        // ---- Q tile -> QS (pre-scaled by SCALE)
        #pragma unroll
        for (int mt = 0; mt < 4; ++mt) acc[mt] = (f32x4){0.f, 0.f, 0.f, 0.f};
        #pragma unroll
        for (int ks = 0; ks < 6; ++ks) {
            bf16x8 bfr;
            if (PACKED) {
                bfr = *(const bf16x8*)(fqQ + ks * 512);
            } else {
                const float* wpq = wq + (ks * 32 + quad * 8) * 576 + colL;
                #pragma unroll
                for (int j = 0; j < 8; ++j) bfr[j] = (__bf16)wpq[j * 576];
            }
            #pragma unroll
            for (int mt = 0; mt < 4; ++mt) {
                bf16x8 afr = *(const bf16x8*)(REGA + (mt * 16 + l15) * 200 + ks * 32 + quad * 8);
                acc[mt] = __builtin_amdgcn_mfma_f32_16x16x32_bf16(afr, bfr, acc[mt], 0, 0, 0);
            }
        }
        {
            float bv = b_qkv[colL];
            #pragma unroll
            for (int mt = 0; mt < 4; ++mt)
                #pragma unroll
                for (int r = 0; r < 4; ++r)
                    QS[(mt * 16 + quad * 4 + r) * 200 + colL] = f2bf((acc[mt][r] + bv) * SCALE);
        }
        // ---- K tile -> KS
        #pragma unroll
        for (int mt = 0; mt < 4; ++mt) acc[mt] = (f32x4){0.f, 0.f, 0.f, 0.f};
        #pragma unroll
        for (int ks = 0; ks < 6; ++ks) {
            bf16x8 bfr;
            if (PACKED) {
                bfr = *(const bf16x8*)(fqK + ks * 512);
            } else {
                const float* wpq = wq + (ks * 32 + quad * 8) * 576 + 192 + colL;
                #pragma unroll
                for (int j = 0; j < 8; ++j) bfr[j] = (__bf16)wpq[j * 576];
            }
            #pragma unroll
            for (int mt = 0; mt < 4; ++mt) {
                bf16x8 afr = *(const bf16x8*)(REGA + (mt * 16 + l15) * 200 + ks * 32 + quad * 8);
                acc[mt] = __builtin_amdgcn_mfma_f32_16x16x32_bf16(afr, bfr, acc[mt], 0, 0, 0);
            }
        }
        {
            float bv = b_qkv[192 + colL];
            #pragma unroll
            for (int mt = 0; mt < 4; ++mt)
                #pragma unroll
                for (int r = 0; r < 4; ++r)
                    KS[(mt * 16 + quad * 4 + r) * 200 + colL] = f2bf(acc[mt][r] + bv);
        }
        // ---- V tile -> registers (XS still live)
        #pragma unroll
        for (int mt = 0; mt < 4; ++mt) accV[mt] = (f32x4){0.f, 0.f, 0.f, 0.f};
        #pragma unroll
        for (int ks = 0; ks < 6; ++ks) {
            bf16x8 bfr;
            if (PACKED) {
                bfr = *(const bf16x8*)(fqV + ks * 512);
            } else {
                const float* wpq = wq + (ks * 32 + quad * 8) * 576 + 384 + colL;
                #pragma unroll
                for (int j = 0; j < 8; ++j) bfr[j] = (__bf16)wpq[j * 576];
            }
            #pragma unroll
            for (int mt = 0; mt < 4; ++mt) {
                bf16x8 afr = *(const bf16x8*)(REGA + (mt * 16 + l15) * 200 + ks * 32 + quad * 8);
                accV[mt] = __builtin_amdgcn_mfma_f32_16x16x32_bf16(afr, bfr, accV[mt], 0, 0, 0);
            }
        }
    }
    __syncthreads();                                  // bar2: all XS reads done
    // ---- V store transposed over XS: VT[feat][token], stride 64, XOR swizzle.
    {
        float bv = b_qkv[384 + colL];
        #pragma unroll
        for (int mt = 0; mt < 4; ++mt) {
            ushort4 pk;
            pk.x = f2bf(accV[mt][0] + bv);
            pk.y = f2bf(accV[mt][1] + bv);
            pk.z = f2bf(accV[mt][2] + bv);
            pk.w = f2bf(accV[mt][3] + bv);
            int t0 = mt * 16 + quad * 4;
            int g  = (t0 >> 3) ^ (colL & 7);
            *(ushort4*)(REGA + colL * 64 + g * 8 + (t0 & 7)) = pk;
        }
    }
    __syncthreads();                                  // bar3: Q,K,V visible

    // ---- Phase 3a: S = Q Kt + bias(+mask baked), softmax. Wave pair = head.
    const int w  = w2 >> 1;        // head 0..5
    const int mh = (w2 & 1) * 2;   // mt base: 0 or 2 (rows 0..31 / 32..63)
    unsigned short* myP = QS + w2 * 2048;             // P over B+C, 32x64 swz per wave
    float sv[2][4][4];
    {
        f32x4 sa[2][4];
        #pragma unroll
        for (int mi = 0; mi < 2; ++mi)
            #pragma unroll
            for (int nt = 0; nt < 4; ++nt) sa[mi][nt] = (f32x4){0.f, 0.f, 0.f, 0.f};
        bf16x8 kf[4];
        #pragma unroll
        for (int nt = 0; nt < 4; ++nt)
            kf[nt] = *(const bf16x8*)(KS + (nt * 16 + l15) * 200 + w * 32 + quad * 8);
        #pragma unroll
        for (int mi = 0; mi < 2; ++mi) {
            bf16x8 afr = *(const bf16x8*)(QS + ((mh + mi) * 16 + l15) * 200 + w * 32 + quad * 8);
            #pragma unroll
            for (int nt = 0; nt < 4; ++nt)
                sa[mi][nt] = __builtin_amdgcn_mfma_f32_16x16x32_bf16(afr, kf[nt], sa[mi][nt], 0, 0, 0);
        }
        __syncthreads();                              // bar4: all QS/KS reads done
        const bool mH = (wh == 31), mW = (ww == 31);
        if (PACKED) {
            const unsigned short* bt = btab + ((((mH ? 2 : 0) + (mW ? 1 : 0)) * 6 + w) << 12);
            #pragma unroll
            for (int mi = 0; mi < 2; ++mi)
                #pragma unroll
                for (int nt = 0; nt < 4; ++nt)
                    #pragma unroll
                    for (int r = 0; r < 4; ++r) {
                        int row = (mh + mi) * 16 + quad * 4 + r;
                        int col = nt * 16 + l15;
                        sv[mi][nt][r] = sa[mi][nt][r] + bf2f(bt[row * 64 + col]);
                    }
        } else {
            #pragma unroll
            for (int mi = 0; mi < 2; ++mi)
                #pragma unroll
                for (int nt = 0; nt < 4; ++nt)
                    #pragma unroll
                    for (int r = 0; r < 4; ++r) {
                        int row = (mh + mi) * 16 + quad * 4 + r;
                        int col = nt * 16 + l15;
                        int r1 = row >> 3, c1 = row & 7, r2 = col >> 3, c2 = col & 7;
                        float v = sa[mi][nt][r]
                                + (float)RELH[((r1 - r2 + 7) * 15 + (c1 - c2 + 7)) * 6 + w];
                        if ((mH && ((r1 < 4) != (r2 < 4))) || (mW && ((c1 < 4) != (c2 < 4))))
                            v = -1e30f;
                        sv[mi][nt][r] = v;
                    }
        }
        // row softmax: each row lives in 4 regs x 16 lanes of one quad-group
        #pragma unroll
        for (int mi = 0; mi < 2; ++mi)
            #pragma unroll
            for (int r = 0; r < 4; ++r) {
                float m = fmaxf(fmaxf(sv[mi][0][r], sv[mi][1][r]),
                                fmaxf(sv[mi][2][r], sv[mi][3][r]));
                m = fmaxf(m, __shfl_xor(m, 1));
                m = fmaxf(m, __shfl_xor(m, 2));
                m = fmaxf(m, __shfl_xor(m, 4));
                m = fmaxf(m, __shfl_xor(m, 8));
                float s = 0.f;
                #pragma unroll
                for (int nt = 0; nt < 4; ++nt) {
                    float p = __expf(sv[mi][nt][r] - m);
                    sv[mi][nt][r] = p;
                    s += p;
                }
                s += __shfl_xor(s, 1);
                s += __shfl_xor(s, 2);
                s += __shfl_xor(s, 4);
                s += __shfl_xor(s, 8);
                float inv = 1.f / s;
                #pragma unroll
                for (int nt = 0; nt < 4; ++nt) sv[mi][nt][r] *= inv;
            }
        // P write (own region, swizzled; writer == reader, no barrier needed)
        #pragma unroll
        for (int mi = 0; mi < 2; ++mi)
            #pragma unroll
            for (int nt = 0; nt < 4; ++nt)
                #pragma unroll
                for (int r = 0; r < 4; ++r) {
                    int row = mi * 16 + quad * 4 + r;          // local 0..31
                    int col = nt * 16 + l15;                   // 0..63
                    myP[row * 64 + (((col >> 3) ^ (row & 7)) << 3) + (col & 7)]
                        = f2bf(sv[mi][nt][r]);
                }
    }

    // ---- Phase 3b: O = P @ V
    {
        f32x4 oa[2][2];
        #pragma unroll
        for (int mi = 0; mi < 2; ++mi) {
            oa[mi][0] = (f32x4){0.f,0.f,0.f,0.f};
            oa[mi][1] = (f32x4){0.f,0.f,0.f,0.f};
        }
        #pragma unroll
        for (int ks2 = 0; ks2 < 2; ++ks2) {
            bf16x8 vf[2];
            #pragma unroll
            for (int nt2 = 0; nt2 < 2; ++nt2) {
                int fr = w * 32 + nt2 * 16 + l15;              // feature row of VT
                int g  = (ks2 * 4 + quad) ^ (fr & 7);
                vf[nt2] = *(const bf16x8*)(REGA + fr * 64 + g * 8);
            }
            #pragma unroll
            for (int mi = 0; mi < 2; ++mi) {
                int row2 = mi * 16 + l15;                      // local P row
                int g2   = (ks2 * 4 + quad) ^ (row2 & 7);
                bf16x8 pf = *(const bf16x8*)(myP + row2 * 64 + g2 * 8);
                #pragma unroll
                for (int nt2 = 0; nt2 < 2; ++nt2)
                    oa[mi][nt2] = __builtin_amdgcn_mfma_f32_16x16x32_bf16(pf, vf[nt2], oa[mi][nt2], 0, 0, 0);
            }
        }
        __syncthreads();                              // bar5: all VT reads done
        unsigned short* OS = REGA;                    // O over VT region, 64x200
        #pragma unroll
        for (int mi = 0; mi < 2; ++mi)
            #pragma unroll
            for (int nt2 = 0; nt2 < 2; ++nt2)
                #pragma unroll
                for (int r = 0; r < 4; ++r)
                    OS[((mh + mi) * 16 + quad * 4 + r) * 200 + w * 32 + nt2 * 16 + l15]
                        = f2bf(oa[mi][nt2][r]);
    }
    __syncthreads();                                  // bar6: O visible

    // ---- Phase 4: out = OS @ w_lin + b_lin, rolled row offsets from ROWOFF
    {
        const unsigned short* OS = REGA;
        int ntg = w2;                                  // 0..11, one col-tile per wave
        const unsigned short* fl = wp + 110592 + ntg * 3072 + lane * 8;
        f32x4 acc[4];
        #pragma unroll
        for (int mt = 0; mt < 4; ++mt) acc[mt] = (f32x4){0.f, 0.f, 0.f, 0.f};
        #pragma unroll
        for (int ks = 0; ks < 6; ++ks) {
            bf16x8 bfr;
            if (PACKED) {
                bfr = *(const bf16x8*)(fl + ks * 512);
            } else {
                const float* wpq = wl + (ks * 32 + quad * 8) * 192 + ntg * 16 + l15;
                #pragma unroll
                for (int j = 0; j < 8; ++j) bfr[j] = (__bf16)wpq[j * 192];
            }
            #pragma unroll
            for (int mt = 0; mt < 4; ++mt) {
                bf16x8 afr = *(const bf16x8*)(OS + (mt * 16 + l15) * 200 + ks * 32 + quad * 8);
                acc[mt] = __builtin_amdgcn_mfma_f32_16x16x32_bf16(afr, bfr, acc[mt], 0, 0, 0);
            }
        }
        int col  = ntg * 16 + l15;                     // 0..191
        float bv = b_lin[col];
        #pragma unroll
        for (int mt = 0; mt < 4; ++mt)
            #pragma unroll
            for (int r = 0; r < 4; ++r) {
                int row = mt * 16 + quad * 4 + r;
                out[ROWOFF[row] + col] = acc[mt][r] + bv;
            }
    }
}

// ---------------------------------------------------------------------------
extern "C" void kernel_launch(void* const* d_in, const int* in_sizes, int n_in,
                              void* d_out, int out_size, void* d_ws, size_t ws_size,
                              hipStream_t stream) {
    const float* x  = (const float*)d_in[0];   // [4,256,256,192] fp32
    const float* wq = (const float*)d_in[1];   // [192,576]
    const float* bq = (const float*)d_in[2];   // [576]
    const float* wl = (const float*)d_in[3];   // [192,192]
    const float* bl = (const float*)d_in[4];   // [192]
    const float* rp = (const float*)d_in[5];   // [225,6]
    (void)in_sizes; (void)n_in;

    if (ws_size >= 491520 && d_ws != nullptr) {
        unsigned short* wpk = (unsigned short*)d_ws;
        unsigned short* bt  = wpk + 147456;
        pack_w<<<576, 256, 0, stream>>>(wq, wl, wpk);
        pack_bias<<<384, 256, 0, stream>>>(rp, bt);
        wmsa_fused<true><<<4096, 768, 0, stream>>>(x, wq, bq, wl, bl, rp, wpk, bt, (float*)d_out);
    } else {
        wmsa_fused<false><<<4096, 768, 0, stream>>>(x, wq, bq, wl, bl, rp, nullptr, nullptr, (float*)d_out);
    }
}